// Round 1
// baseline (1621.870 us; speedup 1.0000x reference)
//
#include <hip/hip_runtime.h>

// RandomMFGL: out[o][g] = (1/4) * sum_n [ (sum_i A[n][o][i] * x[i][f]) @ W[n][f][g] + b[n][g] ]
// A: [4][4096][16384] fp32 (1.07 GB, streamed once -> HBM-bound, floor ~170us)
// Strategy: register-tiled rank-1 GEMM (lane owns 4 rows x 4 f), x transposed+staged
// in LDS (double-buffered, XOR-swizzled), 16-way split-K with fp32 atomics into h,
// tiny epilogue applies W/b/mean.

#define N_ENS 4
#define N_OUT 4096
#define N_IN  16384
#define ROWS  (N_ENS * N_OUT)      // 16384 rows of A (row = n*4096 + o)
#define GSPLIT 16                  // split-K factor
#define ICHUNK (N_IN / GSPLIT)     // 1024 i per block
#define SROUND 256                 // i per LDS staging round
#define NROUND (ICHUNK / SROUND)   // 4
#define NSTEP  (SROUND / 4)        // 64 steps of 4 i

// ---------------- kernel 1: transpose x [16384][16] -> xT [16][16384] ----------------
__global__ __launch_bounds__(256) void k_transpose(const float* __restrict__ x,
                                                   float* __restrict__ xT) {
    int idx = blockIdx.x * 256 + threadIdx.x;   // 0 .. 262143
    int i = idx >> 4;
    int f = idx & 15;
    xT[f * N_IN + i] = x[idx];
}

// ---------------- kernel 2: h[row][f] += sum_i A[row][i] * xT[f][i] ----------------
__global__ __launch_bounds__(256, 4) void k_main(const float* __restrict__ A,
                                                 const float* __restrict__ xT,
                                                 float* __restrict__ h) {
    __shared__ float xs[2][16][SROUND];   // 32 KB, double-buffered, XOR-swizzled

    const int rb   = blockIdx.x & 63;     // 64 row-blocks of 256 rows
    const int g    = blockIdx.x >> 6;     // 16 K-splits
    const int tid  = threadIdx.x;
    const int wave = tid >> 6;            // 0..3
    const int lane = tid & 63;
    const int o_sub = lane & 15;          // row within wave tile
    const int f_sub = lane >> 4;          // f group (4 consecutive f per lane)
    const int i0 = g * ICHUNK;
    const int rowbase = rb * 256 + wave * 64 + o_sub;   // lane's row 0; rows rowbase+16k

    const float* Arow = A + (size_t)rowbase * N_IN + i0;

    float acc[4][4];
#pragma unroll
    for (int k = 0; k < 4; ++k)
#pragma unroll
        for (int j = 0; j < 4; ++j) acc[k][j] = 0.0f;

    // staging: 16 KB of xT per round; each wave stages 4 f-rows (f = c*4 + wave),
    // lane handles quad `lane`; physical LDS quad p holds global quad p ^ (f>>2)
    float4 pf[4];
    const int stg_f[4] = {wave, 4 + wave, 8 + wave, 12 + wave};

    auto stage_load = [&](int r) {
        const int ibase = i0 + r * SROUND;
#pragma unroll
        for (int c = 0; c < 4; ++c) {
            int f = stg_f[c];
            pf[c] = *(const float4*)(xT + (size_t)f * N_IN + ibase + (lane << 2));
        }
    };
    auto stage_write = [&](int buf) {
#pragma unroll
        for (int c = 0; c < 4; ++c) {
            int f = stg_f[c];
            int s = f >> 2;
            *(float4*)&xs[buf][f][(lane ^ s) << 2] = pf[c];
        }
    };

    stage_load(0);
    stage_write(0);
    __syncthreads();

    int buf = 0;
    for (int r = 0; r < NROUND; ++r) {
        if (r + 1 < NROUND) stage_load(r + 1);   // loads stay in flight over compute

        const float* Ap = Arow + r * SROUND;
#pragma unroll 4
        for (int q = 0; q < NSTEP; ++q) {
            float4 a[4];
#pragma unroll
            for (int k = 0; k < 4; ++k)
                a[k] = *(const float4*)(Ap + (size_t)k * 16 * N_IN + (q << 2));
            float4 xv[4];
#pragma unroll
            for (int j = 0; j < 4; ++j)
                xv[j] = *(const float4*)&xs[buf][f_sub * 4 + j][(q ^ f_sub) << 2];
#pragma unroll
            for (int k = 0; k < 4; ++k) {
#pragma unroll
                for (int j = 0; j < 4; ++j) {
                    acc[k][j] = fmaf(a[k].x, xv[j].x, acc[k][j]);
                    acc[k][j] = fmaf(a[k].y, xv[j].y, acc[k][j]);
                    acc[k][j] = fmaf(a[k].z, xv[j].z, acc[k][j]);
                    acc[k][j] = fmaf(a[k].w, xv[j].w, acc[k][j]);
                }
            }
        }

        if (r + 1 < NROUND) stage_write(buf ^ 1);
        __syncthreads();
        buf ^= 1;
    }

    // split-K reduction: device-scope fp32 atomics (16 adders per element total)
#pragma unroll
    for (int k = 0; k < 4; ++k) {
        int row = rowbase + 16 * k;
#pragma unroll
        for (int j = 0; j < 4; ++j)
            atomicAdd(&h[(size_t)row * 16 + f_sub * 4 + j], acc[k][j]);
    }
}

// ---------------- kernel 3: out[o][g] = 0.25 * sum_n (sum_f h[n][o][f]*W[n][f][g] + b[n][g]) ----------------
__global__ __launch_bounds__(256) void k_out(const float* __restrict__ h,
                                             const float* __restrict__ Ws,
                                             const float* __restrict__ bs,
                                             float* __restrict__ out) {
    __shared__ float Wsm[N_ENS * 16 * 16];
    __shared__ float bsm[N_ENS * 16];
    int tid = threadIdx.x;
#pragma unroll
    for (int r = 0; r < 4; ++r) Wsm[tid + 256 * r] = Ws[tid + 256 * r];
    if (tid < 64) bsm[tid] = bs[tid];
    __syncthreads();

    int idx = blockIdx.x * 256 + tid;   // 0..65535
    int o = idx >> 4;
    int gg = idx & 15;
    float s = 0.0f;
#pragma unroll
    for (int n = 0; n < N_ENS; ++n) {
        const float* hr = h + ((size_t)(n * N_OUT + o) << 4);
        float t = 0.0f;
#pragma unroll
        for (int f = 0; f < 16; ++f)
            t = fmaf(hr[f], Wsm[n * 256 + f * 16 + gg], t);
        s += t + bsm[n * 16 + gg];
    }
    out[idx] = 0.25f * s;
}

extern "C" void kernel_launch(void* const* d_in, const int* in_sizes, int n_in,
                              void* d_out, int out_size, void* d_ws, size_t ws_size,
                              hipStream_t stream) {
    const float* x  = (const float*)d_in[0];   // [1, 16384, 16]
    const float* As = (const float*)d_in[1];   // [4, 4096, 16384]
    const float* Ws = (const float*)d_in[2];   // [4, 16, 16]
    const float* bs = (const float*)d_in[3];   // [4, 16]
    float* out = (float*)d_out;                // [1, 4096, 16]

    float* h  = (float*)d_ws;                          // 1 MB: [16384][16]
    float* xT = (float*)((char*)d_ws + (1 << 20));     // 1 MB: [16][16384]

    // h must be zeroed every call (ws is re-poisoned to 0xAA before each launch)
    hipMemsetAsync(h, 0, (size_t)ROWS * 16 * sizeof(float), stream);
    k_transpose<<<(N_IN * 16) / 256, 256, 0, stream>>>(x, xT);
    k_main<<<64 * GSPLIT, 256, 0, stream>>>(As, xT, h);
    k_out<<<(N_OUT * 16) / 256, 256, 0, stream>>>(h, Ws, bs, out);
}

// Round 2
// 1415.233 us; speedup vs baseline: 1.1460x; 1.1460x over previous
//
#include <hip/hip_runtime.h>

// RandomMFGL: out[o][g] = (1/4) * sum_n [ (A[n] @ x) @ W[n] + b[n] ]
// A: [4][4096][16384] fp32 = 1.07 GB streamed once -> HBM-bound, floor ~175us.
//
// k_main: lane = one A-row. Per iteration a lane loads its own 64B line
// (4x float4, zero cross-lane duplication -> 1KB unique per load inst) and
// does 256 FMAs against wave-UNIFORM x values (compiler emits s_load_dwordx16;
// FMA takes the SGPR operand directly). No LDS, no barriers, no transpose.
// Split-K=32 partials into ws (deterministic, no atomics, no memset needed),
// then a coalesced tree-reduce + tiny W/b/mean epilogue.

#define N_ENS 4
#define N_OUT 4096
#define N_IN  16384
#define ROWS  (N_ENS * N_OUT)      // 16384 rows (row = n*4096 + o)
#define GSPLIT 32                  // split-K factor
#define ICHUNK (N_IN / GSPLIT)     // 512 i per (row, split)

// ---------------- kernel 1: hp[split][row][f] = sum_{i in chunk} A[row][i] * x[i][f] ----------------
__global__ __launch_bounds__(256, 6) void k_main(const float* __restrict__ A,
                                                 const float* __restrict__ x,
                                                 float* __restrict__ hp) {
    const int split  = blockIdx.x & (GSPLIT - 1);   // 0..31
    const int rowblk = blockIdx.x >> 5;             // 0..63
    const int row = rowblk * 256 + threadIdx.x;     // lane owns this row
    const int i0 = split * ICHUNK;

    const float* Ap  = A + (size_t)row * N_IN + i0;
    const float* xp0 = x + (size_t)i0 * 16;         // wave-uniform base

    float acc[16];
#pragma unroll
    for (int f = 0; f < 16; ++f) acc[f] = 0.0f;

    for (int s = 0; s < ICHUNK / 16; ++s) {         // 32 iterations, 64 B of A each
        float4 av4[4];
#pragma unroll
        for (int q = 0; q < 4; ++q)
            av4[q] = *(const float4*)(Ap + s * 16 + q * 4);
        const float* af = (const float*)av4;        // lane's 16 consecutive A values
        const float* xp = xp0 + (size_t)s * 256;    // uniform: 16 rows of x, 16 f each

#pragma unroll
        for (int ii = 0; ii < 16; ++ii) {
            const float av = af[ii];
#pragma unroll
            for (int f = 0; f < 16; ++f)
                acc[f] = fmaf(av, xp[ii * 16 + f], acc[f]);   // xp[..] is SGPR-uniform
        }
    }

    float* outp = hp + ((size_t)split * ROWS + row) * 16;   // 64 B per lane, contiguous
#pragma unroll
    for (int f = 0; f < 16; ++f) outp[f] = acc[f];
}

// ---------------- kernel 2: h[row][f] = sum_split hp[split][row][f] ----------------
__global__ __launch_bounds__(256) void k_hsum(const float* __restrict__ hp,
                                              float* __restrict__ h) {
    int t = blockIdx.x * 256 + threadIdx.x;   // 0 .. 262143
    float s = 0.0f;
#pragma unroll
    for (int sp = 0; sp < GSPLIT; ++sp)
        s += hp[(size_t)sp * (ROWS * 16) + t];
    h[t] = s;
}

// ---------------- kernel 3: out[o][g] = 0.25 * sum_n (sum_f h[n][o][f]*W[n][f][g] + b[n][g]) ----------------
__global__ __launch_bounds__(256) void k_out(const float* __restrict__ h,
                                             const float* __restrict__ Ws,
                                             const float* __restrict__ bs,
                                             float* __restrict__ out) {
    __shared__ float Wsm[N_ENS * 16 * 16];
    __shared__ float bsm[N_ENS * 16];
    int tid = threadIdx.x;
#pragma unroll
    for (int r = 0; r < 4; ++r) Wsm[tid + 256 * r] = Ws[tid + 256 * r];
    if (tid < 64) bsm[tid] = bs[tid];
    __syncthreads();

    int idx = blockIdx.x * 256 + tid;   // 0..65535
    int o = idx >> 4;
    int gg = idx & 15;
    float s = 0.0f;
#pragma unroll
    for (int n = 0; n < N_ENS; ++n) {
        const float* hr = h + ((size_t)(n * N_OUT + o) << 4);
        float t = 0.0f;
#pragma unroll
        for (int f = 0; f < 16; ++f)
            t = fmaf(hr[f], Wsm[n * 256 + f * 16 + gg], t);
        s += t + bsm[n * 16 + gg];
    }
    out[idx] = 0.25f * s;
}

extern "C" void kernel_launch(void* const* d_in, const int* in_sizes, int n_in,
                              void* d_out, int out_size, void* d_ws, size_t ws_size,
                              hipStream_t stream) {
    const float* x  = (const float*)d_in[0];   // [1, 16384, 16]
    const float* As = (const float*)d_in[1];   // [4, 4096, 16384]
    const float* Ws = (const float*)d_in[2];   // [4, 16, 16]
    const float* bs = (const float*)d_in[3];   // [4, 16]
    float* out = (float*)d_out;                // [1, 4096, 16]

    float* hp = (float*)d_ws;                                   // 32 MB: [32][16384][16]
    float* h  = (float*)((char*)d_ws + (size_t)32 * 1024 * 1024); // 1 MB: [16384][16]

    // hp/h are fully overwritten every call -> no memset needed despite 0xAA poison.
    k_main<<<64 * GSPLIT, 256, 0, stream>>>(As, x, hp);
    k_hsum<<<(ROWS * 16) / 256, 256, 0, stream>>>(hp, h);
    k_out<<<(N_OUT * 16) / 256, 256, 0, stream>>>(h, Ws, bs, out);
}